// Round 1
// baseline (1380.381 us; speedup 1.0000x reference)
//
#include <hip/hip_runtime.h>

// ---------------------------------------------------------------------------
// Cl(4,1): 32 blades, metric (+,+,+,+,-). Compile-time Cayley sign table.
// C[a][b] = sign of e_a * e_b  (result blade = a ^ b).
// ---------------------------------------------------------------------------
struct Signs { float v[32][32]; };
static constexpr Signs mk_signs() {
    Signs s{};
    for (int a = 0; a < 32; ++a)
        for (int b = 0; b < 32; ++b) {
            int c = 0;
            int t = a >> 1;
            while (t) { c ^= (__builtin_popcount(t & b) & 1); t >>= 1; }
            if (a & b & 16) c ^= 1;           // e5*e5 = -1
            s.v[a][b] = c ? -1.f : 1.f;
        }
    return s;
}
static constexpr Signs SG = mk_signs();

// result[k] = sum_a sign(a, a^k) * d[a] * p[a^k]   (fully unrolled, signs fold
// into v_fma source-negate modifiers; all arrays stay in registers)
__device__ __forceinline__ void gp32(const float* __restrict__ d,
                                     const float* __restrict__ p,
                                     float* __restrict__ o) {
#pragma unroll
    for (int k = 0; k < 32; ++k) {
        float a0 = 0.f, a1 = 0.f;
#pragma unroll
        for (int a = 0; a < 32; a += 2) {
            a0 = fmaf(SG.v[a][a ^ k] * d[a], p[a ^ k], a0);
            a1 = fmaf(SG.v[a + 1][(a + 1) ^ k] * d[a + 1], p[(a + 1) ^ k], a1);
        }
        o[k] = a0 + a1;
    }
}

__device__ __forceinline__ void nrm32(float* __restrict__ v) {
    float s0 = 0.f, s1 = 0.f, s2 = 0.f, s3 = 0.f;
#pragma unroll
    for (int k = 0; k < 32; k += 4) {
        s0 = fmaf(v[k],     v[k],     s0);
        s1 = fmaf(v[k + 1], v[k + 1], s1);
        s2 = fmaf(v[k + 2], v[k + 2], s2);
        s3 = fmaf(v[k + 3], v[k + 3], s3);
    }
    float rs = rsqrtf((s0 + s1) + (s2 + s3) + 1e-12f);
#pragma unroll
    for (int k = 0; k < 32; ++k) v[k] *= rs;
}

// delta = b_in_slice + x_row @ W_in_slice,  then delta[0] += 1
// LDS layouts padded to stride 36 floats per head -> <=2-way bank conflicts.
__device__ __forceinline__ void embed32(const float* __restrict__ sWin,
                                        const float* __restrict__ sBin,
                                        const float* __restrict__ xrow,
                                        int h, float* __restrict__ D) {
#pragma unroll
    for (int j = 0; j < 32; j += 4) {
        float4 bv = *(const float4*)&sBin[h * 36 + j];
        D[j] = bv.x; D[j + 1] = bv.y; D[j + 2] = bv.z; D[j + 3] = bv.w;
    }
#pragma unroll
    for (int dd = 0; dd < 6; ++dd) {
        float xd = xrow[dd];
#pragma unroll
        for (int j = 0; j < 32; j += 4) {
            float4 w = *(const float4*)&sWin[(dd * 16 + h) * 36 + j];
            D[j]     = fmaf(xd, w.x, D[j]);
            D[j + 1] = fmaf(xd, w.y, D[j + 1]);
            D[j + 2] = fmaf(xd, w.z, D[j + 2]);
            D[j + 3] = fmaf(xd, w.w, D[j + 3]);
        }
    }
    D[0] += 1.0f;
}

// out[b,t,n,:] = x_row + b_out + sum_{h,k} psi[h][k] * W_out[h*32+k][:]
__device__ __forceinline__ void emit_out(const float* __restrict__ P,
                                         const float* __restrict__ sWout,
                                         const float* __restrict__ xrow,
                                         const float* __restrict__ bo,
                                         int h, int b, int n, int t,
                                         float* __restrict__ out) {
    float pd[6];
#pragma unroll
    for (int dd = 0; dd < 6; ++dd) {
        float a0 = 0.f, a1 = 0.f, a2 = 0.f, a3 = 0.f;
#pragma unroll
        for (int k = 0; k < 32; k += 4) {
            float4 w = *(const float4*)&sWout[(dd * 16 + h) * 36 + k];
            a0 = fmaf(P[k],     w.x, a0);
            a1 = fmaf(P[k + 1], w.y, a1);
            a2 = fmaf(P[k + 2], w.z, a2);
            a3 = fmaf(P[k + 3], w.w, a3);
        }
        pd[dd] = (a0 + a1) + (a2 + a3);
    }
    // reduce over 16 head-lanes (lane = h + 16*slot)
#pragma unroll
    for (int m = 1; m < 16; m <<= 1) {
#pragma unroll
        for (int dd = 0; dd < 6; ++dd) pd[dd] += __shfl_xor(pd[dd], m, 64);
    }
    if (h == 0) {
        float* o = out + (((size_t)b * 256 + t) * 64 + n) * 6;
#pragma unroll
        for (int dd = 0; dd < 6; ++dd) o[dd] = xrow[dd] + pd[dd] + bo[dd];
    }
}

// ---------------------------------------------------------------------------
// Kernel A: per (chain, head, chunk) compute chunk product T_c (L=32 deltas),
// renormalized each multiply. Block = 1 chain, 128 threads = 16 heads x 8 chunks.
// ---------------------------------------------------------------------------
__global__ __launch_bounds__(128, 2)
void kA(const float* __restrict__ x, const float* __restrict__ W_in,
        const float* __restrict__ b_in, float* __restrict__ wsT) {
    __shared__ float sWin[6 * 16 * 36];
    __shared__ float sBin[16 * 36];
    __shared__ float sX[256 * 6];
    const int tid = threadIdx.x;
    const int chain = blockIdx.x;
    const int b = chain >> 6, n = chain & 63;

    for (int e = tid; e < 3072; e += 128) {
        int dd = e >> 9, r = e & 511;
        sWin[(dd * 16 + (r >> 5)) * 36 + (r & 31)] = W_in[dd * 512 + r];
    }
    for (int e = tid; e < 512; e += 128)
        sBin[(e >> 5) * 36 + (e & 31)] = b_in[e];
    for (int r = tid; r < 256; r += 128) {
        const float* src = x + (((size_t)b * 256 + r) * 64 + n) * 6;
#pragma unroll
        for (int dd = 0; dd < 6; ++dd) sX[r * 6 + dd] = src[dd];
    }
    __syncthreads();

    const int h = tid & 15, c = tid >> 4;
    float T[32], D[32], Nn[32];
#pragma unroll
    for (int k = 0; k < 32; ++k) T[k] = (k == 0) ? 1.f : 0.f;

#pragma unroll 1
    for (int i = 0; i < 32; i += 2) {
        embed32(sWin, sBin, &sX[(c * 32 + i) * 6], h, D);
        gp32(D, T, Nn);  nrm32(Nn);
        embed32(sWin, sBin, &sX[(c * 32 + i + 1) * 6], h, D);
        gp32(D, Nn, T);  nrm32(T);
    }
    float* dst = wsT + (((size_t)chain * 16 + h) * 8 + c) * 32;
#pragma unroll
    for (int k = 0; k < 32; k += 4)
        *(float4*)&dst[k] = make_float4(T[k], T[k + 1], T[k + 2], T[k + 3]);
}

// ---------------------------------------------------------------------------
// Kernel B: per (chain, head) sequential scan of the 8 chunk totals:
// Q_c = T_{c-1} ... T_0 (Q_0 = identity), stored BEFORE each update.
// ---------------------------------------------------------------------------
__global__ __launch_bounds__(128, 2)
void kB(const float* __restrict__ wsT, float* __restrict__ wsQ) {
    const int idx = blockIdx.x * 128 + threadIdx.x;   // < 16384 chain-heads
    const size_t base = (size_t)idx * 8 * 32;
    float Q[32], Tc[32], Nn[32];
#pragma unroll
    for (int k = 0; k < 32; ++k) Q[k] = (k == 0) ? 1.f : 0.f;

#pragma unroll 1
    for (int c = 0; c < 8; c += 2) {
        float* qd = wsQ + base + (size_t)c * 32;
#pragma unroll
        for (int k = 0; k < 32; k += 4)
            *(float4*)&qd[k] = make_float4(Q[k], Q[k + 1], Q[k + 2], Q[k + 3]);
        const float* ts = wsT + base + (size_t)c * 32;
#pragma unroll
        for (int k = 0; k < 32; k += 4) {
            float4 v = *(const float4*)&ts[k];
            Tc[k] = v.x; Tc[k + 1] = v.y; Tc[k + 2] = v.z; Tc[k + 3] = v.w;
        }
        gp32(Tc, Q, Nn);  nrm32(Nn);

        qd = wsQ + base + (size_t)(c + 1) * 32;
#pragma unroll
        for (int k = 0; k < 32; k += 4)
            *(float4*)&qd[k] = make_float4(Nn[k], Nn[k + 1], Nn[k + 2], Nn[k + 3]);
        ts = wsT + base + (size_t)(c + 1) * 32;
#pragma unroll
        for (int k = 0; k < 32; k += 4) {
            float4 v = *(const float4*)&ts[k];
            Tc[k] = v.x; Tc[k + 1] = v.y; Tc[k + 2] = v.z; Tc[k + 3] = v.w;
        }
        gp32(Tc, Nn, Q);  nrm32(Q);
    }
}

// ---------------------------------------------------------------------------
// Kernel C: per (chain, head, chunk) replay chunk from prefix Q_c; each step
// emit out[b,t,n,:] (head-reduced via shfl within the wave).
// ---------------------------------------------------------------------------
__global__ __launch_bounds__(128, 2)
void kC(const float* __restrict__ x, const float* __restrict__ W_in,
        const float* __restrict__ b_in, const float* __restrict__ W_out,
        const float* __restrict__ b_out, const float* __restrict__ wsQ,
        float* __restrict__ out) {
    __shared__ float sWin[6 * 16 * 36];
    __shared__ float sWout[6 * 16 * 36];
    __shared__ float sBin[16 * 36];
    __shared__ float sX[256 * 6];
    const int tid = threadIdx.x;
    const int chain = blockIdx.x;
    const int b = chain >> 6, n = chain & 63;

    for (int e = tid; e < 3072; e += 128) {
        int dd = e >> 9, r = e & 511;
        sWin [(dd * 16 + (r >> 5)) * 36 + (r & 31)] = W_in [dd * 512 + r];
        sWout[(dd * 16 + (r >> 5)) * 36 + (r & 31)] = W_out[r * 6 + dd];
    }
    for (int e = tid; e < 512; e += 128)
        sBin[(e >> 5) * 36 + (e & 31)] = b_in[e];
    for (int r = tid; r < 256; r += 128) {
        const float* src = x + (((size_t)b * 256 + r) * 64 + n) * 6;
#pragma unroll
        for (int dd = 0; dd < 6; ++dd) sX[r * 6 + dd] = src[dd];
    }
    __syncthreads();

    const int h = tid & 15, c = tid >> 4;
    float bo[6];
#pragma unroll
    for (int dd = 0; dd < 6; ++dd) bo[dd] = b_out[dd];

    float P[32], D[32], Nn[32];
    {
        const float* qs = wsQ + (((size_t)chain * 16 + h) * 8 + c) * 32;
#pragma unroll
        for (int k = 0; k < 32; k += 4) {
            float4 v = *(const float4*)&qs[k];
            P[k] = v.x; P[k + 1] = v.y; P[k + 2] = v.z; P[k + 3] = v.w;
        }
    }

#pragma unroll 1
    for (int i = 0; i < 32; i += 2) {
        const int t0 = c * 32 + i;
        embed32(sWin, sBin, &sX[t0 * 6], h, D);
        gp32(D, P, Nn);  nrm32(Nn);
        emit_out(Nn, sWout, &sX[t0 * 6], bo, h, b, n, t0, out);

        embed32(sWin, sBin, &sX[(t0 + 1) * 6], h, D);
        gp32(D, Nn, P);  nrm32(P);
        emit_out(P, sWout, &sX[(t0 + 1) * 6], bo, h, b, n, t0 + 1, out);
    }
}

// ---------------------------------------------------------------------------
extern "C" void kernel_launch(void* const* d_in, const int* in_sizes, int n_in,
                              void* d_out, int out_size, void* d_ws, size_t ws_size,
                              hipStream_t stream) {
    const float* x     = (const float*)d_in[0];
    const float* W_in  = (const float*)d_in[1];
    const float* b_in  = (const float*)d_in[2];
    const float* W_out = (const float*)d_in[3];
    const float* b_out = (const float*)d_in[4];
    float* out = (float*)d_out;

    float* wsT = (float*)d_ws;                      // 1024*16*8*32 floats = 16.8 MB
    float* wsQ = wsT + (size_t)1024 * 16 * 8 * 32;  // same size

    kA<<<1024, 128, 0, stream>>>(x, W_in, b_in, wsT);
    kB<<<128, 128, 0, stream>>>(wsT, wsQ);
    kC<<<1024, 128, 0, stream>>>(x, W_in, b_in, W_out, b_out, wsQ, out);
}

// Round 2
// 608.655 us; speedup vs baseline: 2.2679x; 2.2679x over previous
//
#include <hip/hip_runtime.h>

// ---------------------------------------------------------------------------
// Cl(4,1): 32 blades, metric (+,+,+,+,-). Compile-time Cayley sign table.
// C[a][b] = sign of e_a * e_b  (result blade = a ^ b).
// ---------------------------------------------------------------------------
struct Signs { float v[32][32]; };
static constexpr Signs mk_signs() {
    Signs s{};
    for (int a = 0; a < 32; ++a)
        for (int b = 0; b < 32; ++b) {
            int c = 0;
            int t = a >> 1;
            while (t) { c ^= (__builtin_popcount(t & b) & 1); t >>= 1; }
            if (a & b & 16) c ^= 1;           // e5*e5 = -1
            s.v[a][b] = c ? -1.f : 1.f;
        }
    return s;
}
static constexpr Signs SG = mk_signs();

// result[k] = sum_a sign(a, a^k) * d[a] * p[a^k]   (fully unrolled, signs fold
// into v_fma source-negate modifiers; all arrays stay in registers)
__device__ __forceinline__ void gp32(const float* __restrict__ d,
                                     const float* __restrict__ p,
                                     float* __restrict__ o) {
#pragma unroll
    for (int k = 0; k < 32; ++k) {
        float a0 = 0.f, a1 = 0.f;
#pragma unroll
        for (int a = 0; a < 32; a += 2) {
            a0 = fmaf(SG.v[a][a ^ k] * d[a], p[a ^ k], a0);
            a1 = fmaf(SG.v[a + 1][(a + 1) ^ k] * d[a + 1], p[(a + 1) ^ k], a1);
        }
        o[k] = a0 + a1;
    }
}

__device__ __forceinline__ void nrm32(float* __restrict__ v) {
    float s0 = 0.f, s1 = 0.f, s2 = 0.f, s3 = 0.f;
#pragma unroll
    for (int k = 0; k < 32; k += 4) {
        s0 = fmaf(v[k],     v[k],     s0);
        s1 = fmaf(v[k + 1], v[k + 1], s1);
        s2 = fmaf(v[k + 2], v[k + 2], s2);
        s3 = fmaf(v[k + 3], v[k + 3], s3);
    }
    float rs = rsqrtf((s0 + s1) + (s2 + s3) + 1e-12f);
#pragma unroll
    for (int k = 0; k < 32; ++k) v[k] *= rs;
}

// delta = b_in_slice + x_row @ W_in_slice,  then delta[0] += 1
// LDS layouts padded to stride 36 floats per head -> <=2-way bank conflicts.
__device__ __forceinline__ void embed32(const float* __restrict__ sWin,
                                        const float* __restrict__ sBin,
                                        const float* __restrict__ xrow,
                                        int h, float* __restrict__ D) {
#pragma unroll
    for (int j = 0; j < 32; j += 4) {
        float4 bv = *(const float4*)&sBin[h * 36 + j];
        D[j] = bv.x; D[j + 1] = bv.y; D[j + 2] = bv.z; D[j + 3] = bv.w;
    }
#pragma unroll
    for (int dd = 0; dd < 6; ++dd) {
        float xd = xrow[dd];
#pragma unroll
        for (int j = 0; j < 32; j += 4) {
            float4 w = *(const float4*)&sWin[(dd * 16 + h) * 36 + j];
            D[j]     = fmaf(xd, w.x, D[j]);
            D[j + 1] = fmaf(xd, w.y, D[j + 1]);
            D[j + 2] = fmaf(xd, w.z, D[j + 2]);
            D[j + 3] = fmaf(xd, w.w, D[j + 3]);
        }
    }
    D[0] += 1.0f;
}

// out[b,t,n,:] = x_row + b_out + sum_{h,k} psi[h][k] * W_out[h*32+k][:]
// All 16 head-lanes end with the full sums (butterfly); lanes h<6 each store
// one dword -> a single coalesced 24B store per (slot, t).
__device__ __forceinline__ void emit_out(const float* __restrict__ P,
                                         const float* __restrict__ sWout,
                                         const float* __restrict__ xrow,
                                         const float* __restrict__ bo,
                                         int h, int b, int n, int t,
                                         float* __restrict__ out) {
    float pd[6];
#pragma unroll
    for (int dd = 0; dd < 6; ++dd) {
        float a0 = 0.f, a1 = 0.f, a2 = 0.f, a3 = 0.f;
#pragma unroll
        for (int k = 0; k < 32; k += 4) {
            float4 w = *(const float4*)&sWout[(dd * 16 + h) * 36 + k];
            a0 = fmaf(P[k],     w.x, a0);
            a1 = fmaf(P[k + 1], w.y, a1);
            a2 = fmaf(P[k + 2], w.z, a2);
            a3 = fmaf(P[k + 3], w.w, a3);
        }
        pd[dd] = (a0 + a1) + (a2 + a3);
    }
#pragma unroll
    for (int m = 1; m < 16; m <<= 1) {
#pragma unroll
        for (int dd = 0; dd < 6; ++dd) pd[dd] += __shfl_xor(pd[dd], m, 64);
    }
    // compile-time-indexed select (no runtime-indexed array -> no scratch)
    float v = pd[0] + xrow[0] + bo[0];
    v = (h == 1) ? pd[1] + xrow[1] + bo[1] : v;
    v = (h == 2) ? pd[2] + xrow[2] + bo[2] : v;
    v = (h == 3) ? pd[3] + xrow[3] + bo[3] : v;
    v = (h == 4) ? pd[4] + xrow[4] + bo[4] : v;
    v = (h == 5) ? pd[5] + xrow[5] + bo[5] : v;
    if (h < 6) {
        float* o = out + (((size_t)b * 256 + t) * 64 + n) * 6;
        o[h] = v;
    }
}

// ---------------------------------------------------------------------------
// Kernel A: per (chain, head, chunk) compute chunk product T_c (L=32 deltas),
// renormalized each multiply. Block = 1 chain, 128 threads = 16 heads x 8 chunks.
// ---------------------------------------------------------------------------
__global__ __launch_bounds__(128, 1)
void kA(const float* __restrict__ x, const float* __restrict__ W_in,
        const float* __restrict__ b_in, float* __restrict__ wsT) {
    __shared__ float sWin[6 * 16 * 36];
    __shared__ float sBin[16 * 36];
    __shared__ float sX[256 * 6];
    const int tid = threadIdx.x;
    const int chain = blockIdx.x;
    const int b = chain >> 6, n = chain & 63;

    for (int e = tid; e < 3072; e += 128) {
        int dd = e >> 9, r = e & 511;
        sWin[(dd * 16 + (r >> 5)) * 36 + (r & 31)] = W_in[dd * 512 + r];
    }
    for (int e = tid; e < 512; e += 128)
        sBin[(e >> 5) * 36 + (e & 31)] = b_in[e];
    for (int r = tid; r < 256; r += 128) {
        const float* src = x + (((size_t)b * 256 + r) * 64 + n) * 6;
#pragma unroll
        for (int dd = 0; dd < 6; ++dd) sX[r * 6 + dd] = src[dd];
    }
    __syncthreads();

    const int h = tid & 15, c = tid >> 4;
    float T[32], D[32], Nn[32];
#pragma unroll
    for (int k = 0; k < 32; ++k) T[k] = (k == 0) ? 1.f : 0.f;

#pragma unroll 1
    for (int i = 0; i < 32; i += 2) {
        embed32(sWin, sBin, &sX[(c * 32 + i) * 6], h, D);
        gp32(D, T, Nn);  nrm32(Nn);
        embed32(sWin, sBin, &sX[(c * 32 + i + 1) * 6], h, D);
        gp32(D, Nn, T);  nrm32(T);
    }
    float* dst = wsT + (((size_t)chain * 16 + h) * 8 + c) * 32;
#pragma unroll
    for (int k = 0; k < 32; k += 4)
        *(float4*)&dst[k] = make_float4(T[k], T[k + 1], T[k + 2], T[k + 3]);
}

// ---------------------------------------------------------------------------
// Kernel B: per (chain, head) sequential scan of the 8 chunk totals:
// Q_c = T_{c-1} ... T_0 (Q_0 = identity), stored BEFORE each update.
// ---------------------------------------------------------------------------
__global__ __launch_bounds__(128, 1)
void kB(const float* __restrict__ wsT, float* __restrict__ wsQ) {
    const int idx = blockIdx.x * 128 + threadIdx.x;   // < 16384 chain-heads
    const size_t base = (size_t)idx * 8 * 32;
    float Q[32], Tc[32], Nn[32];
#pragma unroll
    for (int k = 0; k < 32; ++k) Q[k] = (k == 0) ? 1.f : 0.f;

#pragma unroll 1
    for (int c = 0; c < 8; c += 2) {
        float* qd = wsQ + base + (size_t)c * 32;
#pragma unroll
        for (int k = 0; k < 32; k += 4)
            *(float4*)&qd[k] = make_float4(Q[k], Q[k + 1], Q[k + 2], Q[k + 3]);
        const float* ts = wsT + base + (size_t)c * 32;
#pragma unroll
        for (int k = 0; k < 32; k += 4) {
            float4 v = *(const float4*)&ts[k];
            Tc[k] = v.x; Tc[k + 1] = v.y; Tc[k + 2] = v.z; Tc[k + 3] = v.w;
        }
        gp32(Tc, Q, Nn);  nrm32(Nn);

        qd = wsQ + base + (size_t)(c + 1) * 32;
#pragma unroll
        for (int k = 0; k < 32; k += 4)
            *(float4*)&qd[k] = make_float4(Nn[k], Nn[k + 1], Nn[k + 2], Nn[k + 3]);
        ts = wsT + base + (size_t)(c + 1) * 32;
#pragma unroll
        for (int k = 0; k < 32; k += 4) {
            float4 v = *(const float4*)&ts[k];
            Tc[k] = v.x; Tc[k + 1] = v.y; Tc[k + 2] = v.z; Tc[k + 3] = v.w;
        }
        gp32(Tc, Nn, Q);  nrm32(Q);
    }
}

// ---------------------------------------------------------------------------
// Kernel C: per (chain, head, chunk) replay chunk from prefix Q_c; each step
// emit out[b,t,n,:] (head-reduced via shfl within the wave).
// ---------------------------------------------------------------------------
__global__ __launch_bounds__(128, 1)
void kC(const float* __restrict__ x, const float* __restrict__ W_in,
        const float* __restrict__ b_in, const float* __restrict__ W_out,
        const float* __restrict__ b_out, const float* __restrict__ wsQ,
        float* __restrict__ out) {
    __shared__ float sWin[6 * 16 * 36];
    __shared__ float sWout[6 * 16 * 36];
    __shared__ float sBin[16 * 36];
    __shared__ float sX[256 * 6];
    const int tid = threadIdx.x;
    const int chain = blockIdx.x;
    const int b = chain >> 6, n = chain & 63;

    for (int e = tid; e < 3072; e += 128) {
        int dd = e >> 9, r = e & 511;
        sWin [(dd * 16 + (r >> 5)) * 36 + (r & 31)] = W_in [dd * 512 + r];
        sWout[(dd * 16 + (r >> 5)) * 36 + (r & 31)] = W_out[r * 6 + dd];
    }
    for (int e = tid; e < 512; e += 128)
        sBin[(e >> 5) * 36 + (e & 31)] = b_in[e];
    for (int r = tid; r < 256; r += 128) {
        const float* src = x + (((size_t)b * 256 + r) * 64 + n) * 6;
#pragma unroll
        for (int dd = 0; dd < 6; ++dd) sX[r * 6 + dd] = src[dd];
    }
    __syncthreads();

    const int h = tid & 15, c = tid >> 4;
    float bo[6];
#pragma unroll
    for (int dd = 0; dd < 6; ++dd) bo[dd] = b_out[dd];

    float P[32], D[32], Nn[32];
    {
        const float* qs = wsQ + (((size_t)chain * 16 + h) * 8 + c) * 32;
#pragma unroll
        for (int k = 0; k < 32; k += 4) {
            float4 v = *(const float4*)&qs[k];
            P[k] = v.x; P[k + 1] = v.y; P[k + 2] = v.z; P[k + 3] = v.w;
        }
    }

#pragma unroll 1
    for (int i = 0; i < 32; i += 2) {
        const int t0 = c * 32 + i;
        embed32(sWin, sBin, &sX[t0 * 6], h, D);
        gp32(D, P, Nn);  nrm32(Nn);
        emit_out(Nn, sWout, &sX[t0 * 6], bo, h, b, n, t0, out);

        embed32(sWin, sBin, &sX[(t0 + 1) * 6], h, D);
        gp32(D, Nn, P);  nrm32(P);
        emit_out(P, sWout, &sX[(t0 + 1) * 6], bo, h, b, n, t0 + 1, out);
    }
}

// ---------------------------------------------------------------------------
extern "C" void kernel_launch(void* const* d_in, const int* in_sizes, int n_in,
                              void* d_out, int out_size, void* d_ws, size_t ws_size,
                              hipStream_t stream) {
    const float* x     = (const float*)d_in[0];
    const float* W_in  = (const float*)d_in[1];
    const float* b_in  = (const float*)d_in[2];
    const float* W_out = (const float*)d_in[3];
    const float* b_out = (const float*)d_in[4];
    float* out = (float*)d_out;

    float* wsT = (float*)d_ws;                      // 1024*16*8*32 floats = 16.8 MB
    float* wsQ = wsT + (size_t)1024 * 16 * 8 * 32;  // same size

    kA<<<1024, 128, 0, stream>>>(x, W_in, b_in, wsT);
    kB<<<128, 128, 0, stream>>>(wsT, wsQ);
    kC<<<1024, 128, 0, stream>>>(x, W_in, b_in, W_out, b_out, wsQ, out);
}

// Round 4
// 462.904 us; speedup vs baseline: 2.9820x; 1.3149x over previous
//
#include <hip/hip_runtime.h>
#include <stdint.h>

typedef __fp16   pkv2 __attribute__((ext_vector_type(2)));   // cvt_pkrtz result
typedef _Float16 h2   __attribute__((ext_vector_type(2)));   // fdot2 operand

// ---------------------------------------------------------------------------
// Cl(4,1) Cayley sign table: SG.v[a][b] = sign of e_a * e_b (blade = a ^ b).
// ---------------------------------------------------------------------------
struct Signs { float v[32][32]; };
static constexpr Signs mk_signs() {
    Signs s{};
    for (int a = 0; a < 32; ++a)
        for (int b = 0; b < 32; ++b) {
            int c = 0;
            int t = a >> 1;
            while (t) { c ^= (__builtin_popcount(t & b) & 1); t >>= 1; }
            if (a & b & 16) c ^= 1;           // e5*e5 = -1
            s.v[a][b] = c ? -1.f : 1.f;
        }
    return s;
}
static constexpr Signs SG = mk_signs();

// ---- f16 pair helpers ------------------------------------------------------
__device__ __forceinline__ uint32_t pk(float a, float b) {
#if __has_builtin(__builtin_amdgcn_cvt_pkrtz)
    union { pkv2 h; uint32_t u; } u;
    u.h = __builtin_amdgcn_cvt_pkrtz(a, b);
    return u.u;
#else
    union { _Float16 f[2]; uint32_t u; } u;
    u.f[0] = (_Float16)a; u.f[1] = (_Float16)b; return u.u;
#endif
}

__device__ __forceinline__ float dot2u(uint32_t w, uint32_t xp, float c) {
    union { uint32_t u; h2 h; } a, b; a.u = w; b.u = xp;
#if __has_builtin(__builtin_amdgcn_fdot2)
    return __builtin_amdgcn_fdot2(a.h, b.h, c, false);
#else
    return c + (float)a.h.x * (float)b.h.x + (float)a.h.y * (float)b.h.y;
#endif
}

#define XP_ONE 0x00003C00u   // half2(1.0, 0.0)

// ---- delta only (step 0: psi = delta since psi0 = e0) ----------------------
__device__ __forceinline__ void stepD(const uint32_t* __restrict__ wih,
                                      uint32_t xp0, uint32_t xp1, uint32_t xp2,
                                      float* __restrict__ U) {
#pragma unroll
    for (int a = 0; a < 32; ++a) {
        uint4 w = *(const uint4*)(wih + a * 4);
        float d = dot2u(w.w, XP_ONE, (a == 0) ? 1.f : 0.f);
        d = dot2u(w.z, xp2, d);
        d = dot2u(w.y, xp1, d);
        d = dot2u(w.x, xp0, d);
        U[a] = d;
    }
}

// ---- fused embed + geometric product: O = delta(x_t) (x) U -----------------
__device__ __forceinline__ void stepGP(const uint32_t* __restrict__ wih,
                                       uint32_t xp0, uint32_t xp1, uint32_t xp2,
                                       const float* __restrict__ U,
                                       float* __restrict__ O) {
#pragma unroll
    for (int a = 0; a < 32; ++a) {
        uint4 w = *(const uint4*)(wih + a * 4);
        float d = dot2u(w.w, XP_ONE, (a == 0) ? 1.f : 0.f);
        d = dot2u(w.z, xp2, d);
        d = dot2u(w.y, xp1, d);
        d = dot2u(w.x, xp0, d);
        if (a == 0) {
#pragma unroll
            for (int j = 0; j < 32; ++j) O[j] = d * U[j];
        } else {
#pragma unroll
            for (int j = 0; j < 32; ++j)
                O[a ^ j] = fmaf(SG.v[a][j] * d, U[j], O[a ^ j]);
        }
    }
}

// ---- plain f32 GP for the chunk scan: O = D (x) P --------------------------
__device__ __forceinline__ void gpF(const float* __restrict__ D,
                                    const float* __restrict__ P,
                                    float* __restrict__ O) {
#pragma unroll
    for (int a = 0; a < 32; ++a) {
        float d = D[a];
        if (a == 0) {
#pragma unroll
            for (int j = 0; j < 32; ++j) O[j] = d * P[j];
        } else {
#pragma unroll
            for (int j = 0; j < 32; ++j)
                O[a ^ j] = fmaf(SG.v[a][j] * d, P[j], O[a ^ j]);
        }
    }
}

__device__ __forceinline__ void nrmF(float* __restrict__ v) {
    float s0 = 0.f, s1 = 0.f, s2 = 0.f, s3 = 0.f;
#pragma unroll
    for (int k = 0; k < 32; k += 4) {
        s0 = fmaf(v[k], v[k], s0);  s1 = fmaf(v[k + 1], v[k + 1], s1);
        s2 = fmaf(v[k + 2], v[k + 2], s2);  s3 = fmaf(v[k + 3], v[k + 3], s3);
    }
    float rs = rsqrtf((s0 + s1) + (s2 + s3) + 1e-12f);
#pragma unroll
    for (int k = 0; k < 32; ++k) v[k] *= rs;
}

// ---- normalize + project + head-reduce + store; returns 1/|P| --------------
__device__ __forceinline__ float emitOut(const float* __restrict__ P,
                                         const uint32_t* __restrict__ woh,
                                         float4 xv, float2 xw,
                                         const float* __restrict__ bo,
                                         int h, int b, int n, int t,
                                         float* __restrict__ out) {
    float s0 = 0.f, s1 = 0.f, s2 = 0.f, s3 = 0.f;
#pragma unroll
    for (int k = 0; k < 32; k += 4) {
        s0 = fmaf(P[k], P[k], s0);  s1 = fmaf(P[k + 1], P[k + 1], s1);
        s2 = fmaf(P[k + 2], P[k + 2], s2);  s3 = fmaf(P[k + 3], P[k + 3], s3);
    }
    float rs = rsqrtf((s0 + s1) + (s2 + s3) + 1e-12f);
    uint32_t ph[16];
#pragma unroll
    for (int m = 0; m < 16; ++m) ph[m] = pk(rs * P[2 * m], rs * P[2 * m + 1]);
    float pd[6];
#pragma unroll
    for (int dd = 0; dd < 6; ++dd) {
        uint4 w0 = *(const uint4*)(woh + dd * 16);
        uint4 w1 = *(const uint4*)(woh + dd * 16 + 4);
        uint4 w2 = *(const uint4*)(woh + dd * 16 + 8);
        uint4 w3 = *(const uint4*)(woh + dd * 16 + 12);
        float a0 = dot2u(w0.x, ph[0], 0.f);
        a0 = dot2u(w0.y, ph[1], a0);  a0 = dot2u(w0.z, ph[2], a0);
        a0 = dot2u(w0.w, ph[3], a0);  a0 = dot2u(w1.x, ph[4], a0);
        a0 = dot2u(w1.y, ph[5], a0);  a0 = dot2u(w1.z, ph[6], a0);
        a0 = dot2u(w1.w, ph[7], a0);
        float a1 = dot2u(w2.x, ph[8], 0.f);
        a1 = dot2u(w2.y, ph[9], a1);  a1 = dot2u(w2.z, ph[10], a1);
        a1 = dot2u(w2.w, ph[11], a1); a1 = dot2u(w3.x, ph[12], a1);
        a1 = dot2u(w3.y, ph[13], a1); a1 = dot2u(w3.z, ph[14], a1);
        a1 = dot2u(w3.w, ph[15], a1);
        pd[dd] = a0 + a1;
    }
#pragma unroll
    for (int mm = 1; mm < 16; mm <<= 1) {
#pragma unroll
        for (int dd = 0; dd < 6; ++dd) pd[dd] += __shfl_xor(pd[dd], mm, 64);
    }
    float v = pd[0] + xv.x + bo[0];
    v = (h == 1) ? pd[1] + xv.y + bo[1] : v;
    v = (h == 2) ? pd[2] + xv.z + bo[2] : v;
    v = (h == 3) ? pd[3] + xv.w + bo[3] : v;
    v = (h == 4) ? pd[4] + xw.x + bo[4] : v;
    v = (h == 5) ? pd[5] + xw.y + bo[5] : v;
    if (h < 6)
        out[(((size_t)b * 256 + t) * 64 + n) * 6 + h] = v;
    return rs;
}

#define LOADX(t)                                                   \
    { xv = *(const float4*)&sX[(t) * 8];                           \
      xw = *(const float2*)&sX[(t) * 8 + 4];                       \
      xp0 = pk(xv.x, xv.y); xp1 = pk(xv.z, xv.w); xp2 = pk(xw.x, xw.y); }

// ---------------------------------------------------------------------------
// One block per chain (b,n). 128 threads = 16 heads x 8 chunks of 32 steps.
// Phase A: chunk products (deferred renorm). Phase B: in-LDS Hillis-Steele
// scan over the 8 chunks. Phase C: replay each chunk from its prefix + emit.
// ---------------------------------------------------------------------------
__global__ __launch_bounds__(128, 2)
void versor(const float* __restrict__ x, const float* __restrict__ W_in,
            const float* __restrict__ b_in, const float* __restrict__ W_out,
            const float* __restrict__ b_out, float* __restrict__ out) {
    __shared__ uint32_t sWi[16 * 132];   // [h](stride 132): 32 k x 4 f16-pairs
    __shared__ uint32_t sWo[16 * 100];   // [h](stride 100): 6 dd x 16 k-pairs
    __shared__ float    sX[256 * 8];     // [t](stride 8): 6 x-values
    __shared__ float    sTQ[16 * 265];   // [h](stride 265)[c](stride 33): 32 f32

    const int tid = threadIdx.x;
    const int bid = blockIdx.x;
    const int chain = (bid & 7) * 128 + (bid >> 3);   // XCD-contiguous chains
    const int b = chain >> 6, n = chain & 63;

    // ---- stage weights (f16 pairs) and x-chain (f32) ----
    for (int e = tid; e < 512; e += 128) {
        int h = e >> 5, k = e & 31, col = h * 32 + k;
        float w0 = W_in[0 * 512 + col], w1 = W_in[1 * 512 + col];
        float w2 = W_in[2 * 512 + col], w3 = W_in[3 * 512 + col];
        float w4 = W_in[4 * 512 + col], w5 = W_in[5 * 512 + col];
        float bb = b_in[col];
        *(uint4*)&sWi[h * 132 + k * 4] =
            make_uint4(pk(w0, w1), pk(w2, w3), pk(w4, w5), pk(bb, 0.f));
    }
    for (int e = tid; e < 256; e += 128) {
        int h = e >> 4, m = e & 15;
        const float* r0 = &W_out[(h * 32 + 2 * m) * 6];
#pragma unroll
        for (int dd = 0; dd < 6; ++dd)
            sWo[h * 100 + dd * 16 + m] = pk(r0[dd], r0[6 + dd]);
    }
    for (int r = tid; r < 256; r += 128) {
        const float2* s2 = (const float2*)(x + (((size_t)b * 256 + r) * 64 + n) * 6);
        float2 a0 = s2[0], a1 = s2[1], a2 = s2[2];
        float* dst = &sX[r * 8];
        *(float2*)dst = a0; *(float2*)(dst + 2) = a1; *(float2*)(dst + 4) = a2;
        dst[6] = 0.f; dst[7] = 0.f;
    }
    __syncthreads();

    const int h = tid & 15, c = tid >> 4;
    const uint32_t* wih = &sWi[h * 132];
    const uint32_t* woh = &sWo[h * 100];
    const int t0 = c * 32;

    float bo[6];
#pragma unroll
    for (int dd = 0; dd < 6; ++dd) bo[dd] = b_out[dd];

    float U[32], O[32];
    uint32_t xp0, xp1, xp2; float4 xv; float2 xw;

    // ---- Phase A: chunk product (32 steps, renorm every 8) ----
    LOADX(t0);
    stepD(wih, xp0, xp1, xp2, U);                    // step 0
#pragma unroll 1
    for (int q = 0; q < 15; ++q) {
        LOADX(t0 + 2 * q + 1);
        stepGP(wih, xp0, xp1, xp2, U, O);            // odd step -> O
        if ((q & 3) == 3) {                          // steps 7, 15, 23
            float s0 = 0.f;
#pragma unroll
            for (int k = 0; k < 32; ++k) s0 = fmaf(O[k], O[k], s0);
            float rr = rsqrtf(s0 + 1e-12f);
#pragma unroll
            for (int k = 0; k < 32; ++k) O[k] *= rr;
        }
        LOADX(t0 + 2 * q + 2);
        stepGP(wih, xp0, xp1, xp2, O, U);            // even step -> U
    }
    LOADX(t0 + 31);
    stepGP(wih, xp0, xp1, xp2, U, O);                // step 31 -> O
    nrmF(O);
    {
        float* tq = &sTQ[h * 265 + c * 33];
#pragma unroll
        for (int j = 0; j < 32; ++j) tq[j] = O[j];
    }
    __syncthreads();

    // ---- Phase B: Hillis-Steele inclusive scan over 8 chunks (per head) ----
#pragma unroll 1
    for (int r = 0; r < 3; ++r) {
        const int s = 1 << r;
        const bool act = (c >= s);
        float Prt[32];
        if (act) {
            const float* ps = &sTQ[h * 265 + (c - s) * 33];
#pragma unroll
            for (int j = 0; j < 32; ++j) Prt[j] = ps[j];
        }
        __syncthreads();
        if (act) {
            float R[32];
            gpF(O, Prt, R);                          // mine (later) x earlier
#pragma unroll
            for (int j = 0; j < 32; ++j) O[j] = R[j];
            float* tq = &sTQ[h * 265 + c * 33];
#pragma unroll
            for (int j = 0; j < 32; ++j) tq[j] = O[j];
        }
        __syncthreads();
    }

    // ---- Phase C: replay chunk from exclusive prefix Q_c = P_{c-1} ----
    if (c == 0) {
#pragma unroll
        for (int j = 0; j < 32; ++j) U[j] = (j == 0) ? 1.f : 0.f;
    } else {
        const float* qs = &sTQ[h * 265 + (c - 1) * 33];
#pragma unroll
        for (int j = 0; j < 32; ++j) U[j] = qs[j];
    }

#pragma unroll 1
    for (int q = 0; q < 16; ++q) {
        const int t = t0 + 2 * q;
        LOADX(t);
        stepGP(wih, xp0, xp1, xp2, U, O);
        emitOut(O, woh, xv, xw, bo, h, b, n, t, out);
        LOADX(t + 1);
        stepGP(wih, xp0, xp1, xp2, O, U);
        float rs = emitOut(U, woh, xv, xw, bo, h, b, n, t + 1, out);
        if ((q & 3) == 3) {                          // rescale every 8 steps
#pragma unroll
            for (int j = 0; j < 32; ++j) U[j] *= rs;
        }
    }
}

// ---------------------------------------------------------------------------
extern "C" void kernel_launch(void* const* d_in, const int* in_sizes, int n_in,
                              void* d_out, int out_size, void* d_ws, size_t ws_size,
                              hipStream_t stream) {
    const float* x     = (const float*)d_in[0];
    const float* W_in  = (const float*)d_in[1];
    const float* b_in  = (const float*)d_in[2];
    const float* W_out = (const float*)d_in[3];
    const float* b_out = (const float*)d_in[4];
    float* out = (float*)d_out;

    versor<<<1024, 128, 0, stream>>>(x, W_in, b_in, W_out, b_out, out);
}

// Round 5
// 335.110 us; speedup vs baseline: 4.1192x; 1.3813x over previous
//
#include <hip/hip_runtime.h>
#include <stdint.h>

typedef __fp16   pkv2 __attribute__((ext_vector_type(2)));   // cvt_pkrtz result
typedef _Float16 h2   __attribute__((ext_vector_type(2)));   // fdot2 operand

// ---------------------------------------------------------------------------
// Cl(4,1) Cayley sign table: SG.v[a][b] = sign of e_a * e_b (blade = a ^ b).
// ---------------------------------------------------------------------------
struct Signs { float v[32][32]; };
static constexpr Signs mk_signs() {
    Signs s{};
    for (int a = 0; a < 32; ++a)
        for (int b = 0; b < 32; ++b) {
            int c = 0;
            int t = a >> 1;
            while (t) { c ^= (__builtin_popcount(t & b) & 1); t >>= 1; }
            if (a & b & 16) c ^= 1;           // e5*e5 = -1
            s.v[a][b] = c ? -1.f : 1.f;
        }
    return s;
}
static constexpr Signs SG = mk_signs();

// ---- f16 pair helpers ------------------------------------------------------
__device__ __forceinline__ uint32_t pk(float a, float b) {
    union { pkv2 h; uint32_t u; } u;
    u.h = __builtin_amdgcn_cvt_pkrtz(a, b);
    return u.u;
}
__device__ __forceinline__ float dot2u(uint32_t w, uint32_t xp, float c) {
    union { uint32_t u; h2 h; } a, b; a.u = w; b.u = xp;
    return __builtin_amdgcn_fdot2(a.h, b.h, c, false);
}
__device__ __forceinline__ void unpk(uint32_t u, float& a, float& b) {
    union { uint32_t u; h2 h; } x; x.u = u;
    a = (float)x.h.x; b = (float)x.h.y;
}

// ---- fused f32 embed + geometric product: O = delta(x_t) (x) U -------------
// FIRST=true: O = delta (psi0 = e0).  Weights from LDS, bias from registers.
template<bool FIRST>
__device__ __forceinline__ void stepF(const float* __restrict__ w03h,
                                      const float* __restrict__ w45h,
                                      const float* __restrict__ bias,
                                      float4 xv, float2 xw,
                                      const float* __restrict__ U,
                                      float* __restrict__ O) {
    float4 w45 = {0.f, 0.f, 0.f, 0.f};
#pragma unroll
    for (int a = 0; a < 32; ++a) {
        float4 w03 = *(const float4*)(w03h + a * 4);
        if ((a & 1) == 0) w45 = *(const float4*)(w45h + (a >> 1) * 4);
        const float w4 = (a & 1) ? w45.z : w45.x;
        const float w5 = (a & 1) ? w45.w : w45.y;
        float d = bias[a] + ((a == 0) ? 1.f : 0.f);
        d = fmaf(xv.x, w03.x, d); d = fmaf(xv.y, w03.y, d);
        d = fmaf(xv.z, w03.z, d); d = fmaf(xv.w, w03.w, d);
        d = fmaf(xw.x, w4, d);    d = fmaf(xw.y, w5, d);
        if (FIRST) {
            O[a] = d;
        } else if (a == 0) {
#pragma unroll
            for (int j = 0; j < 32; ++j) O[j] = d * U[j];
        } else {
#pragma unroll
            for (int j = 0; j < 32; ++j)
                O[a ^ j] = fmaf(SG.v[a][j] * d, U[j], O[a ^ j]);
        }
    }
}

// ---- plain f32 GP for the chunk scan: O = D (x) P --------------------------
__device__ __forceinline__ void gpF(const float* __restrict__ D,
                                    const float* __restrict__ P,
                                    float* __restrict__ O) {
#pragma unroll
    for (int a = 0; a < 32; ++a) {
        float d = D[a];
        if (a == 0) {
#pragma unroll
            for (int j = 0; j < 32; ++j) O[j] = d * P[j];
        } else {
#pragma unroll
            for (int j = 0; j < 32; ++j)
                O[a ^ j] = fmaf(SG.v[a][j] * d, P[j], O[a ^ j]);
        }
    }
}

__device__ __forceinline__ void nrmF(float* __restrict__ v) {
    float s0 = 0.f, s1 = 0.f, s2 = 0.f, s3 = 0.f;
#pragma unroll
    for (int k = 0; k < 32; k += 4) {
        s0 = fmaf(v[k], v[k], s0);  s1 = fmaf(v[k + 1], v[k + 1], s1);
        s2 = fmaf(v[k + 2], v[k + 2], s2);  s3 = fmaf(v[k + 3], v[k + 3], s3);
    }
    float rs = rsqrtf((s0 + s1) + (s2 + s3) + 1e-12f);
#pragma unroll
    for (int k = 0; k < 32; ++k) v[k] *= rs;
}

// ---- normalize + f16 project + head-reduce + store; returns 1/|P| ----------
__device__ __forceinline__ float emitOut(const float* __restrict__ P,
                                         const uint32_t* __restrict__ woh,
                                         float4 xv, float2 xw,
                                         const float* __restrict__ bo,
                                         int h, int b, int n, int t,
                                         float* __restrict__ out) {
    float s0 = 0.f, s1 = 0.f, s2 = 0.f, s3 = 0.f;
#pragma unroll
    for (int k = 0; k < 32; k += 4) {
        s0 = fmaf(P[k], P[k], s0);  s1 = fmaf(P[k + 1], P[k + 1], s1);
        s2 = fmaf(P[k + 2], P[k + 2], s2);  s3 = fmaf(P[k + 3], P[k + 3], s3);
    }
    float rs = rsqrtf((s0 + s1) + (s2 + s3) + 1e-12f);
    uint32_t ph[16];
#pragma unroll
    for (int m = 0; m < 16; ++m) ph[m] = pk(rs * P[2 * m], rs * P[2 * m + 1]);
    float pd[6];
#pragma unroll
    for (int dd = 0; dd < 6; ++dd) {
        uint4 w0 = *(const uint4*)(woh + dd * 16);
        uint4 w1 = *(const uint4*)(woh + dd * 16 + 4);
        uint4 w2 = *(const uint4*)(woh + dd * 16 + 8);
        uint4 w3 = *(const uint4*)(woh + dd * 16 + 12);
        float a0 = dot2u(w0.x, ph[0], 0.f);
        a0 = dot2u(w0.y, ph[1], a0);  a0 = dot2u(w0.z, ph[2], a0);
        a0 = dot2u(w0.w, ph[3], a0);  a0 = dot2u(w1.x, ph[4], a0);
        a0 = dot2u(w1.y, ph[5], a0);  a0 = dot2u(w1.z, ph[6], a0);
        a0 = dot2u(w1.w, ph[7], a0);
        float a1 = dot2u(w2.x, ph[8], 0.f);
        a1 = dot2u(w2.y, ph[9], a1);  a1 = dot2u(w2.z, ph[10], a1);
        a1 = dot2u(w2.w, ph[11], a1); a1 = dot2u(w3.x, ph[12], a1);
        a1 = dot2u(w3.y, ph[13], a1); a1 = dot2u(w3.z, ph[14], a1);
        a1 = dot2u(w3.w, ph[15], a1);
        pd[dd] = a0 + a1;
    }
#pragma unroll
    for (int mm = 1; mm < 16; mm <<= 1) {
#pragma unroll
        for (int dd = 0; dd < 6; ++dd) pd[dd] += __shfl_xor(pd[dd], mm, 64);
    }
    float v = pd[0] + xv.x + bo[0];
    v = (h == 1) ? pd[1] + xv.y + bo[1] : v;
    v = (h == 2) ? pd[2] + xv.z + bo[2] : v;
    v = (h == 3) ? pd[3] + xv.w + bo[3] : v;
    v = (h == 4) ? pd[4] + xw.x + bo[4] : v;
    v = (h == 5) ? pd[5] + xw.y + bo[5] : v;
    if (h < 6)
        out[(((size_t)b * 256 + t) * 64 + n) * 6 + h] = v;
    return rs;
}

#define LOADX(t)                                                   \
    { xv = *(const float4*)&sX[(t) * 8];                           \
      xw = *(const float2*)&sX[(t) * 8 + 4]; }

// ---------------------------------------------------------------------------
// One block per chain (b,n). 128 threads = 16 heads x 8 chunks of 32 steps.
// Phase A: chunk products (f32, deferred renorm). Phase B: in-LDS
// Hillis-Steele scan over the 8 chunks (f16 handoff). Phase C: replay each
// chunk from its exclusive prefix; f16 output projection each step.
// ---------------------------------------------------------------------------
__global__ __launch_bounds__(128, 1)
void versor(const float* __restrict__ x, const float* __restrict__ W_in,
            const float* __restrict__ b_in, const float* __restrict__ W_out,
            const float* __restrict__ b_out, float* __restrict__ out) {
    __shared__ float    sW03[16 * 132];  // [h](132): 32 blades x float4(w0..w3)
    __shared__ float    sW45[16 * 68];   // [h](68): 16 pairs x float4(w4,w5,w4',w5')
    __shared__ uint32_t sWo[16 * 100];   // [h](100): 6 dd x 16 f16-pairs
    __shared__ float    sX[256 * 8];     // [t](8): 6 x-values
    __shared__ uint32_t sTQ[16 * 164];   // [h](164)[c](20): 16 f16-pairs

    const int tid = threadIdx.x;
    const int bid = blockIdx.x;
    const int chain = (bid & 7) * 128 + (bid >> 3);   // XCD-contiguous chains
    const int b = chain >> 6, n = chain & 63;

    // ---- stage: W_in rows 0..3 (f32), rows 4..5 pair-packed, W_out (f16) ----
    for (int e = tid; e < 512; e += 128) {
        const int h = e >> 5, k = e & 31;
#pragma unroll
        for (int dd = 0; dd < 4; ++dd)
            sW03[h * 132 + k * 4 + dd] = W_in[dd * 512 + e];
    }
    for (int e = tid; e < 256; e += 128) {
        const int h = e >> 4, m = e & 15;
        const int col = h * 32 + 2 * m;
        *(float4*)&sW45[h * 68 + m * 4] =
            make_float4(W_in[4 * 512 + col], W_in[5 * 512 + col],
                        W_in[4 * 512 + col + 1], W_in[5 * 512 + col + 1]);
        const float* r0 = &W_out[col * 6];
#pragma unroll
        for (int dd = 0; dd < 6; ++dd)
            sWo[h * 100 + dd * 16 + m] = pk(r0[dd], r0[6 + dd]);
    }
    for (int r = tid; r < 256; r += 128) {
        const float2* s2 = (const float2*)(x + (((size_t)b * 256 + r) * 64 + n) * 6);
        float2 a0 = s2[0], a1 = s2[1], a2 = s2[2];
        float* dst = &sX[r * 8];
        *(float2*)dst = a0; *(float2*)(dst + 2) = a1; *(float2*)(dst + 4) = a2;
        dst[6] = 0.f; dst[7] = 0.f;
    }

    const int h = tid & 15, c = tid >> 4;
    float bias[32];
#pragma unroll
    for (int j = 0; j < 32; j += 4)
        *(float4*)&bias[j] = *(const float4*)&b_in[h * 32 + j];
    float bo[6];
#pragma unroll
    for (int dd = 0; dd < 6; ++dd) bo[dd] = b_out[dd];
    __syncthreads();

    const float*    w03h = &sW03[h * 132];
    const float*    w45h = &sW45[h * 68];
    const uint32_t* woh  = &sWo[h * 100];
    uint32_t*       tqh  = &sTQ[h * 164];
    const int t0 = c * 32;

    float U[32], O[32];
    float4 xv; float2 xw;

    // ---- Phase A: chunk product (32 steps, renorm every 8) ----
    LOADX(t0);
    stepF<true>(w03h, w45h, bias, xv, xw, U, U);      // step 0: U = delta
#pragma unroll 1
    for (int q = 0; q < 15; ++q) {
        LOADX(t0 + 2 * q + 1);
        stepF<false>(w03h, w45h, bias, xv, xw, U, O); // odd step -> O
        if ((q & 3) == 3) {                           // steps 7, 15, 23
            float s0 = 0.f;
#pragma unroll
            for (int k = 0; k < 32; ++k) s0 = fmaf(O[k], O[k], s0);
            float rr = rsqrtf(s0 + 1e-12f);
#pragma unroll
            for (int k = 0; k < 32; ++k) O[k] *= rr;
        }
        LOADX(t0 + 2 * q + 2);
        stepF<false>(w03h, w45h, bias, xv, xw, O, U); // even step -> U
    }
    LOADX(t0 + 31);
    stepF<false>(w03h, w45h, bias, xv, xw, U, O);     // step 31 -> O
    nrmF(O);
#pragma unroll
    for (int mq = 0; mq < 4; ++mq)
        *(uint4*)(tqh + c * 20 + mq * 4) =
            make_uint4(pk(O[8 * mq + 0], O[8 * mq + 1]), pk(O[8 * mq + 2], O[8 * mq + 3]),
                       pk(O[8 * mq + 4], O[8 * mq + 5]), pk(O[8 * mq + 6], O[8 * mq + 7]));
    __syncthreads();

    // ---- Phase B: Hillis-Steele inclusive scan over 8 chunks (per head) ----
#pragma unroll 1
    for (int r = 0; r < 3; ++r) {
        const int s = 1 << r;
        const bool act = (c >= s);
        float Prt[32];
        if (act) {
            const uint32_t* ps = tqh + (c - s) * 20;
#pragma unroll
            for (int mq = 0; mq < 4; ++mq) {
                uint4 v = *(const uint4*)(ps + mq * 4);
                unpk(v.x, Prt[8 * mq + 0], Prt[8 * mq + 1]);
                unpk(v.y, Prt[8 * mq + 2], Prt[8 * mq + 3]);
                unpk(v.z, Prt[8 * mq + 4], Prt[8 * mq + 5]);
                unpk(v.w, Prt[8 * mq + 6], Prt[8 * mq + 7]);
            }
        }
        __syncthreads();
        if (act) {
            float R[32];
            gpF(O, Prt, R);                           // mine (later) x earlier
            nrmF(R);
#pragma unroll
            for (int j = 0; j < 32; ++j) O[j] = R[j];
#pragma unroll
            for (int mq = 0; mq < 4; ++mq)
                *(uint4*)(tqh + c * 20 + mq * 4) =
                    make_uint4(pk(O[8 * mq + 0], O[8 * mq + 1]), pk(O[8 * mq + 2], O[8 * mq + 3]),
                               pk(O[8 * mq + 4], O[8 * mq + 5]), pk(O[8 * mq + 6], O[8 * mq + 7]));
        }
        __syncthreads();
    }

    // ---- Phase C: replay chunk from exclusive prefix Q_c = P_{c-1} ----
    if (c == 0) {
#pragma unroll
        for (int j = 0; j < 32; ++j) U[j] = (j == 0) ? 1.f : 0.f;
    } else {
        const uint32_t* ps = tqh + (c - 1) * 20;
#pragma unroll
        for (int mq = 0; mq < 4; ++mq) {
            uint4 v = *(const uint4*)(ps + mq * 4);
            unpk(v.x, U[8 * mq + 0], U[8 * mq + 1]);
            unpk(v.y, U[8 * mq + 2], U[8 * mq + 3]);
            unpk(v.z, U[8 * mq + 4], U[8 * mq + 5]);
            unpk(v.w, U[8 * mq + 6], U[8 * mq + 7]);
        }
    }

#pragma unroll 1
    for (int q = 0; q < 16; ++q) {
        const int t = t0 + 2 * q;
        LOADX(t);
        stepF<false>(w03h, w45h, bias, xv, xw, U, O);
        emitOut(O, woh, xv, xw, bo, h, b, n, t, out);
        LOADX(t + 1);
        stepF<false>(w03h, w45h, bias, xv, xw, O, U);
        float rs = emitOut(U, woh, xv, xw, bo, h, b, n, t + 1, out);
        if ((q & 3) == 3) {                           // rescale every 8 steps
#pragma unroll
            for (int j = 0; j < 32; ++j) U[j] *= rs;
        }
    }
}

// ---------------------------------------------------------------------------
extern "C" void kernel_launch(void* const* d_in, const int* in_sizes, int n_in,
                              void* d_out, int out_size, void* d_ws, size_t ws_size,
                              hipStream_t stream) {
    const float* x     = (const float*)d_in[0];
    const float* W_in  = (const float*)d_in[1];
    const float* b_in  = (const float*)d_in[2];
    const float* W_out = (const float*)d_in[3];
    const float* b_out = (const float*)d_in[4];
    float* out = (float*)d_out;

    versor<<<1024, 128, 0, stream>>>(x, W_in, b_in, W_out, b_out, out);
}